// Round 2
// baseline (801.629 us; speedup 1.0000x reference)
//
#include <hip/hip_runtime.h>
#include <stdint.h>
#include <stddef.h>

#define T_SEQ 2048
#define WINDOW_SZ 1024

typedef __attribute__((ext_vector_type(4))) float f32x4;
typedef __attribute__((ext_vector_type(8))) short s16x8;

__device__ inline unsigned short f2bf(float f) {
  union { float f; unsigned u; } v; v.f = f;
  unsigned u = v.u;
  return (unsigned short)((u + 0x7fffu + ((u >> 16) & 1u)) >> 16);
}

__device__ inline void gld_lds16(const unsigned short* g, unsigned short* l) {
  __builtin_amdgcn_global_load_lds((const __attribute__((address_space(1))) void*)g,
                                   (__attribute__((address_space(3))) void*)l, 16, 0, 0);
}

// ---------------- fp32 -> bf16 convert (vectorized) ----------------
__global__ __launch_bounds__(256) void cvt_bf16(const float* __restrict__ s,
                                                unsigned short* __restrict__ d, int n4) {
  int i = blockIdx.x * 256 + threadIdx.x;
  if (i >= n4) return;
  float4 v = ((const float4*)s)[i];
  ushort4 o;
  o.x = f2bf(v.x); o.y = f2bf(v.y); o.z = f2bf(v.z); o.w = f2bf(v.w);
  ((ushort4*)d)[i] = o;
}

// ---------------- bf16 GEMM: C[M,N] = A[M,K] @ Bt[N,K]^T (m97 pattern) ----------------
__global__ __launch_bounds__(256) void gemm_bt(const unsigned short* __restrict__ A,
                                               const unsigned short* __restrict__ Bt,
                                               float* __restrict__ C, int M, int N, int K) {
  __shared__ unsigned short As[4096];  // 128 rows x 32 cols bf16
  __shared__ unsigned short Bs[4096];
  const int tid  = threadIdx.x;
  const int wave = tid >> 6, lane = tid & 63;
  const int quad = lane >> 4, l16 = lane & 15;
  const int m0 = blockIdx.y << 7, n0 = blockIdx.x << 7;
  const int wr = (wave >> 1) << 6;
  const int wc = (wave & 1) << 6;
  const int srow = tid >> 2;
  const int scol = (tid & 3) << 3;

  f32x4 acc[4][4] = {};

  const unsigned short* pA0 = A  + (size_t)(m0 + srow) * K + scol;
  const unsigned short* pA1 = A  + (size_t)(m0 + 64 + srow) * K + scol;
  const unsigned short* pB0 = Bt + (size_t)(n0 + srow) * K + scol;
  const unsigned short* pB1 = Bt + (size_t)(n0 + 64 + srow) * K + scol;
  unsigned short* lA0 = As + wave * 512;
  unsigned short* lA1 = As + 2048 + wave * 512;
  unsigned short* lB0 = Bs + wave * 512;
  unsigned short* lB1 = Bs + 2048 + wave * 512;

  for (int k0 = 0; k0 < K; k0 += 32) {
    gld_lds16(pA0 + k0, lA0);
    gld_lds16(pA1 + k0, lA1);
    gld_lds16(pB0 + k0, lB0);
    gld_lds16(pB1 + k0, lB1);
    __syncthreads();
    s16x8 af[4], bfr[4];
#pragma unroll
    for (int i = 0; i < 4; i++) {
      af[i]  = *(const s16x8*)&As[(wr + i * 16 + l16) * 32 + quad * 8];
      bfr[i] = *(const s16x8*)&Bs[(wc + i * 16 + l16) * 32 + quad * 8];
    }
#pragma unroll
    for (int mi = 0; mi < 4; mi++)
#pragma unroll
      for (int ni = 0; ni < 4; ni++)
        acc[mi][ni] = __builtin_amdgcn_mfma_f32_16x16x32_bf16(af[mi], bfr[ni], acc[mi][ni], 0, 0, 0);
    __syncthreads();
  }
#pragma unroll
  for (int mi = 0; mi < 4; mi++)
#pragma unroll
    for (int ni = 0; ni < 4; ni++) {
      int row = m0 + wr + mi * 16 + quad * 4;
      int col = n0 + wc + ni * 16 + l16;
#pragma unroll
      for (int r = 0; r < 4; r++)
        C[(size_t)(row + r) * N + col] = acc[mi][ni][r];
    }
}

// ---------------- fused RMSNorm + RoPE + layout (one block per token) ----------------
// qkv fp32 [T][6144] -> qr bf16 [32][T][128] (PRE-SCALED by 1/sqrt(128)),
// kr bf16 [8][T][128], vt bf16 [8][128][T]
__global__ __launch_bounds__(256) void normrope(const float* __restrict__ qkv,
                                                const float* __restrict__ cosb,
                                                const float* __restrict__ sinb,
                                                const float* __restrict__ wq,
                                                const float* __restrict__ wk,
                                                unsigned short* __restrict__ qr,
                                                unsigned short* __restrict__ kr,
                                                unsigned short* __restrict__ vt) {
  const int t = blockIdx.x, tid = threadIdx.x;
  const float* row = qkv + (size_t)t * 6144;
  float sq = 0.f, sk = 0.f;
#pragma unroll
  for (int i = 0; i < 4; i++) {
    float4 v = ((const float4*)row)[tid + i * 256];
    sq += v.x * v.x + v.y * v.y + v.z * v.z + v.w * v.w;
  }
  {
    float4 v = ((const float4*)(row + 4096))[tid];
    sk = v.x * v.x + v.y * v.y + v.z * v.z + v.w * v.w;
  }
#pragma unroll
  for (int off = 32; off; off >>= 1) { sq += __shfl_xor(sq, off); sk += __shfl_xor(sk, off); }
  __shared__ float red[8];
  if ((tid & 63) == 0) { red[tid >> 6] = sq; red[4 + (tid >> 6)] = sk; }
  __syncthreads();
  sq = red[0] + red[1] + red[2] + red[3];
  sk = red[4] + red[5] + red[6] + red[7];
  const float rq = rsqrtf(sq * (1.f / 4096.f) + 1e-5f) * 0.08838834764831845f; // fold 1/sqrt(HEAD)
  const float rk = rsqrtf(sk * (1.f / 1024.f) + 1e-5f);
  for (int i = tid; i < 4096; i += 256) {
    int h = i >> 7, d = i & 127;
    int pd = (d < 64) ? d + 64 : d - 64;
    float val = row[i] * rq * wq[i];
    float pv  = row[(h << 7) + pd] * rq * wq[(h << 7) + pd];
    float rot = (d < 64) ? -pv : pv;
    float o = val * cosb[t * 128 + d] + rot * sinb[t * 128 + d];
    qr[(size_t)h * T_SEQ * 128 + t * 128 + d] = f2bf(o);
  }
  for (int i = tid; i < 1024; i += 256) {
    int g = i >> 7, d = i & 127;
    int pd = (d < 64) ? d + 64 : d - 64;
    float val = row[4096 + i] * rk * wk[i];
    float pv  = row[4096 + (g << 7) + pd] * rk * wk[(g << 7) + pd];
    float rot = (d < 64) ? -pv : pv;
    float o = val * cosb[t * 128 + d] + rot * sinb[t * 128 + d];
    kr[(size_t)g * T_SEQ * 128 + t * 128 + d] = f2bf(o);
  }
  for (int i = tid; i < 1024; i += 256) {
    int g = i >> 7, d = i & 127;
    vt[(size_t)g * 128 * T_SEQ + (size_t)d * T_SEQ + t] = f2bf(row[5120 + i]);
  }
}

// ---------------- flash attention, sliding window ----------------
// No running max (scores ~N(0,1), |s|<~12 -> raw exp is fp32-safe; softmax is
// shift-invariant so result identical). Per-lane partial denominator, reduced
// once at the end. 64-key chunks. Q pre-scaled. P via bf16 LDS, stride 68 pad.
__global__ __launch_bounds__(256) void attn(const unsigned short* __restrict__ Q,
                                            const unsigned short* __restrict__ Kb,
                                            const unsigned short* __restrict__ Vt,
                                            unsigned short* __restrict__ Y) {
  __shared__ unsigned short Pbuf[4][16 * 68];  // per-wave, 16 q rows x 64 keys, +4 pad
  const int h = blockIdx.x >> 5;
  const int qb = blockIdx.x & 31;
  const int tid = threadIdx.x, wave = tid >> 6, lane = tid & 63;
  const int quad = lane >> 4, l16 = lane & 15;
  const int g = h >> 2;
  const int q0 = qb * 64 + wave * 16;
  const unsigned short* Qh = Q + (size_t)h * T_SEQ * 128;
  const unsigned short* Kg = Kb + (size_t)g * T_SEQ * 128;
  const unsigned short* Vg = Vt + (size_t)g * 128 * T_SEQ;
  unsigned short* Pw = Pbuf[wave];

  s16x8 aq[4];
#pragma unroll
  for (int ks = 0; ks < 4; ks++)
    aq[ks] = *(const s16x8*)&Qh[(size_t)(q0 + l16) * 128 + ks * 32 + quad * 8];

  f32x4 acc[8] = {};
  float lrow[4] = {0.f, 0.f, 0.f, 0.f};

  int kk0 = q0 - (WINDOW_SZ - 1);
  if (kk0 < 0) kk0 = 0;
  kk0 &= ~63;
  for (int kk = kk0; kk <= q0 + 15; kk += 64) {
    // S = Q K^T : four 16-key tiles (all keys kk..kk+63 are in-range reads)
    f32x4 s[4] = {};
#pragma unroll
    for (int ks = 0; ks < 4; ks++) {
#pragma unroll
      for (int ci = 0; ci < 4; ci++) {
        s16x8 b = *(const s16x8*)&Kg[(size_t)(kk + ci * 16 + l16) * 128 + ks * 32 + quad * 8];
        s[ci] = __builtin_amdgcn_mfma_f32_16x16x32_bf16(aq[ks], b, s[ci], 0, 0, 0);
      }
    }
    // mask + exp (no max subtraction) + per-lane denominator + bf16 LDS (A-layout)
#pragma unroll
    for (int ci = 0; ci < 4; ci++) {
      int col = kk + ci * 16 + l16;
#pragma unroll
      for (int r = 0; r < 4; r++) {
        int irow = q0 + quad * 4 + r;
        unsigned dd = (unsigned)(irow - col);
        float e = (dd < (unsigned)WINDOW_SZ) ? __expf(s[ci][r]) : 0.f;
        lrow[r] += e;
        Pw[(quad * 4 + r) * 68 + ci * 16 + l16] = f2bf(e);
      }
    }
    // O += P @ V (same-wave LDS write->read; compiler inserts lgkmcnt waits)
#pragma unroll
    for (int c = 0; c < 2; c++) {
      s16x8 pa = *(const s16x8*)&Pw[l16 * 68 + c * 32 + quad * 8];
#pragma unroll
      for (int n = 0; n < 8; n++) {
        s16x8 bv = *(const s16x8*)&Vg[(size_t)(n * 16 + l16) * T_SEQ + kk + c * 32 + quad * 8];
        acc[n] = __builtin_amdgcn_mfma_f32_16x16x32_bf16(pa, bv, acc[n], 0, 0, 0);
      }
    }
  }
  // reduce denominator across the 16-lane column group (once per wave)
#pragma unroll
  for (int r = 0; r < 4; r++) {
#pragma unroll
    for (int off = 8; off; off >>= 1) lrow[r] += __shfl_xor(lrow[r], off);
    lrow[r] = 1.f / lrow[r];
  }
#pragma unroll
  for (int n = 0; n < 8; n++)
#pragma unroll
    for (int r = 0; r < 4; r++) {
      int irow = q0 + quad * 4 + r;
      Y[(size_t)irow * 4096 + h * 128 + n * 16 + l16] = f2bf(acc[n][r] * lrow[r]);
    }
}

extern "C" void kernel_launch(void* const* d_in, const int* in_sizes, int n_in,
                              void* d_out, int out_size, void* d_ws, size_t ws_size,
                              hipStream_t stream) {
  (void)in_sizes; (void)n_in; (void)out_size; (void)ws_size;
  const float* x     = (const float*)d_in[0];
  const float* cosb  = (const float*)d_in[1];
  const float* sinb  = (const float*)d_in[2];
  const float* Wqkv  = (const float*)d_in[3];
  const float* wq    = (const float*)d_in[4];
  const float* wk    = (const float*)d_in[5];
  const float* Wproj = (const float*)d_in[6];
  float* out = (float*)d_out;

  char* ws = (char*)d_ws;
  unsigned short* x_bf     = (unsigned short*)(ws);                 // 16 MB
  unsigned short* wqkv_bf  = (unsigned short*)(ws + 16777216);      // 48 MB
  unsigned short* wproj_bf = (unsigned short*)(ws + 67108864);      // 32 MB
  float*          qkv      = (float*)(ws + 100663296);              // 48 MB
  unsigned short* qr       = (unsigned short*)(ws + 150994944);     // 16 MB
  unsigned short* kr       = (unsigned short*)(ws + 167772160);     // 4 MB
  unsigned short* vt       = (unsigned short*)(ws + 171966464);     // 4 MB
  unsigned short* y        = (unsigned short*)(ws + 176160768);     // 16 MB

  cvt_bf16<<<(2097152 + 255) / 256, 256, 0, stream>>>(x, x_bf, 2097152);
  cvt_bf16<<<(6291456 + 255) / 256, 256, 0, stream>>>(Wqkv, wqkv_bf, 6291456);
  cvt_bf16<<<(4194304 + 255) / 256, 256, 0, stream>>>(Wproj, wproj_bf, 4194304);
  gemm_bt<<<dim3(48, 16), 256, 0, stream>>>(x_bf, wqkv_bf, qkv, 2048, 6144, 4096);
  normrope<<<2048, 256, 0, stream>>>(qkv, cosb, sinb, wq, wk, qr, kr, vt);
  attn<<<1024, 256, 0, stream>>>(qr, kr, vt, y);
  gemm_bt<<<dim3(32, 16), 256, 0, stream>>>(y, wproj_bf, out, 2048, 4096, 4096);
}

// Round 3
// 563.649 us; speedup vs baseline: 1.4222x; 1.4222x over previous
//
#include <hip/hip_runtime.h>
#include <stdint.h>
#include <stddef.h>

#define T_SEQ 2048
#define WINDOW_SZ 1024

typedef __attribute__((ext_vector_type(4))) float f32x4;
typedef __attribute__((ext_vector_type(8))) short s16x8;

__device__ inline unsigned short f2bf(float f) {
  union { float f; unsigned u; } v; v.f = f;
  unsigned u = v.u;
  return (unsigned short)((u + 0x7fffu + ((u >> 16) & 1u)) >> 16);
}

__device__ inline void gld_lds16(const unsigned short* g, unsigned short* l) {
  __builtin_amdgcn_global_load_lds((const __attribute__((address_space(1))) void*)g,
                                   (__attribute__((address_space(3))) void*)l, 16, 0, 0);
}

// ---------------- fp32 -> bf16 convert (vectorized) ----------------
__global__ __launch_bounds__(256) void cvt_bf16(const float* __restrict__ s,
                                                unsigned short* __restrict__ d, int n4) {
  int i = blockIdx.x * 256 + threadIdx.x;
  if (i >= n4) return;
  float4 v = ((const float4*)s)[i];
  ushort4 o;
  o.x = f2bf(v.x); o.y = f2bf(v.y); o.z = f2bf(v.z); o.w = f2bf(v.w);
  ((ushort4*)d)[i] = o;
}

// ---------------- bf16 GEMM: C[M,N] = A[M,K] @ Bt[N,K]^T (m97 pattern) ----------------
__global__ __launch_bounds__(256) void gemm_bt(const unsigned short* __restrict__ A,
                                               const unsigned short* __restrict__ Bt,
                                               float* __restrict__ C, int M, int N, int K) {
  __shared__ unsigned short As[4096];  // 128 rows x 32 cols bf16
  __shared__ unsigned short Bs[4096];
  const int tid  = threadIdx.x;
  const int wave = tid >> 6, lane = tid & 63;
  const int quad = lane >> 4, l16 = lane & 15;
  const int m0 = blockIdx.y << 7, n0 = blockIdx.x << 7;
  const int wr = (wave >> 1) << 6;
  const int wc = (wave & 1) << 6;
  const int srow = tid >> 2;
  const int scol = (tid & 3) << 3;

  f32x4 acc[4][4] = {};

  const unsigned short* pA0 = A  + (size_t)(m0 + srow) * K + scol;
  const unsigned short* pA1 = A  + (size_t)(m0 + 64 + srow) * K + scol;
  const unsigned short* pB0 = Bt + (size_t)(n0 + srow) * K + scol;
  const unsigned short* pB1 = Bt + (size_t)(n0 + 64 + srow) * K + scol;
  unsigned short* lA0 = As + wave * 512;
  unsigned short* lA1 = As + 2048 + wave * 512;
  unsigned short* lB0 = Bs + wave * 512;
  unsigned short* lB1 = Bs + 2048 + wave * 512;

  for (int k0 = 0; k0 < K; k0 += 32) {
    gld_lds16(pA0 + k0, lA0);
    gld_lds16(pA1 + k0, lA1);
    gld_lds16(pB0 + k0, lB0);
    gld_lds16(pB1 + k0, lB1);
    __syncthreads();
    s16x8 af[4], bfr[4];
#pragma unroll
    for (int i = 0; i < 4; i++) {
      af[i]  = *(const s16x8*)&As[(wr + i * 16 + l16) * 32 + quad * 8];
      bfr[i] = *(const s16x8*)&Bs[(wc + i * 16 + l16) * 32 + quad * 8];
    }
#pragma unroll
    for (int mi = 0; mi < 4; mi++)
#pragma unroll
      for (int ni = 0; ni < 4; ni++)
        acc[mi][ni] = __builtin_amdgcn_mfma_f32_16x16x32_bf16(af[mi], bfr[ni], acc[mi][ni], 0, 0, 0);
    __syncthreads();
  }
#pragma unroll
  for (int mi = 0; mi < 4; mi++)
#pragma unroll
    for (int ni = 0; ni < 4; ni++) {
      int row = m0 + wr + mi * 16 + quad * 4;
      int col = n0 + wc + ni * 16 + l16;
#pragma unroll
      for (int r = 0; r < 4; r++)
        C[(size_t)(row + r) * N + col] = acc[mi][ni][r];
    }
}

// ---------------- fused RMSNorm + RoPE + layout (one block per token) ----------------
// qkv fp32 [T][6144] -> qr bf16 [32][T][128] (PRE-SCALED by log2(e)/sqrt(128)),
// kr bf16 [8][T][128], vt bf16 [8][128][T]
__global__ __launch_bounds__(256) void normrope(const float* __restrict__ qkv,
                                                const float* __restrict__ cosb,
                                                const float* __restrict__ sinb,
                                                const float* __restrict__ wq,
                                                const float* __restrict__ wk,
                                                unsigned short* __restrict__ qr,
                                                unsigned short* __restrict__ kr,
                                                unsigned short* __restrict__ vt) {
  const int t = blockIdx.x, tid = threadIdx.x;
  const float* row = qkv + (size_t)t * 6144;
  float sq = 0.f, sk = 0.f;
#pragma unroll
  for (int i = 0; i < 4; i++) {
    float4 v = ((const float4*)row)[tid + i * 256];
    sq += v.x * v.x + v.y * v.y + v.z * v.z + v.w * v.w;
  }
  {
    float4 v = ((const float4*)(row + 4096))[tid];
    sk = v.x * v.x + v.y * v.y + v.z * v.z + v.w * v.w;
  }
#pragma unroll
  for (int off = 32; off; off >>= 1) { sq += __shfl_xor(sq, off); sk += __shfl_xor(sk, off); }
  __shared__ float red[8];
  if ((tid & 63) == 0) { red[tid >> 6] = sq; red[4 + (tid >> 6)] = sk; }
  __syncthreads();
  sq = red[0] + red[1] + red[2] + red[3];
  sk = red[4] + red[5] + red[6] + red[7];
  // fold 1/sqrt(HEAD) and log2(e) into q scale: attn uses exp2 (exact identity)
  const float rq = rsqrtf(sq * (1.f / 4096.f) + 1e-5f) * (0.08838834764831845f * 1.4426950408889634f);
  const float rk = rsqrtf(sk * (1.f / 1024.f) + 1e-5f);
  for (int i = tid; i < 4096; i += 256) {
    int h = i >> 7, d = i & 127;
    int pd = (d < 64) ? d + 64 : d - 64;
    float val = row[i] * rq * wq[i];
    float pv  = row[(h << 7) + pd] * rq * wq[(h << 7) + pd];
    float rot = (d < 64) ? -pv : pv;
    float o = val * cosb[t * 128 + d] + rot * sinb[t * 128 + d];
    qr[(size_t)h * T_SEQ * 128 + t * 128 + d] = f2bf(o);
  }
  for (int i = tid; i < 1024; i += 256) {
    int g = i >> 7, d = i & 127;
    int pd = (d < 64) ? d + 64 : d - 64;
    float val = row[4096 + i] * rk * wk[i];
    float pv  = row[4096 + (g << 7) + pd] * rk * wk[(g << 7) + pd];
    float rot = (d < 64) ? -pv : pv;
    float o = val * cosb[t * 128 + d] + rot * sinb[t * 128 + d];
    kr[(size_t)g * T_SEQ * 128 + t * 128 + d] = f2bf(o);
  }
  for (int i = tid; i < 1024; i += 256) {
    int g = i >> 7, d = i & 127;
    vt[(size_t)g * 128 * T_SEQ + (size_t)d * T_SEQ + t] = f2bf(row[5120 + i]);
  }
}

// ---------------- flash attention, sliding window, block-shared LDS K/V ----------------
// Block = 512 thr (8 waves) = one KV group, 64 queries, 4 heads.
// Wave = 1 head x 32 queries (two 16-row frags sharing each K-frag load).
// K/V 64-key chunks double-buffered in LDS via global_load_lds, XOR-swizzled
// (swizzle chosen at staging by lane->global remap) for conflict-free b128 reads.
// Softmax: no running max (RMSNormed scores are fp32-exp safe); exp2 with
// log2(e) folded into Q.
__global__ __launch_bounds__(512, 2) void attn(const unsigned short* __restrict__ Q,
                                               const unsigned short* __restrict__ Kb,
                                               const unsigned short* __restrict__ Vt,
                                               unsigned short* __restrict__ Y) {
  __shared__ unsigned short Kbuf[2][64 * 128];   // slot(r,oct)=r*16+(oct^(r&15)) [16B units]
  __shared__ unsigned short Vbuf[2][128 * 64];   // slot(d,oct)=d*8+(oct^(d&7))
  __shared__ unsigned short Pbuf[8][2][16 * 72]; // per-wave P, stride 72 (16B-aligned rows)
  const int qb = blockIdx.x, g = blockIdx.y;
  const int tid = threadIdx.x, wave = tid >> 6, lane = tid & 63;
  const int quad = lane >> 4, l16 = lane & 15;
  const int h = g * 4 + (wave >> 1);
  const int qbase = qb * 64;
  const int q0 = qbase + (wave & 1) * 32;
  const unsigned short* Qh = Q + (size_t)h * T_SEQ * 128;
  const unsigned short* Kg = Kb + (size_t)g * T_SEQ * 128;
  const unsigned short* Vg = Vt + (size_t)g * 128 * T_SEQ;

  // Q A-frags for both 16-row tiles
  s16x8 aq[2][4];
#pragma unroll
  for (int qt = 0; qt < 2; qt++)
#pragma unroll
    for (int ks = 0; ks < 4; ks++)
      aq[qt][ks] = *(const s16x8*)&Qh[(size_t)(q0 + qt * 16 + l16) * 128 + ks * 32 + quad * 8];

  f32x4 acc[2][8] = {};
  float lrow[2][4] = {};

  int lo = qbase - (WINDOW_SZ - 1);
  if (lo < 0) lo = 0;
  lo &= ~63;

  // --- staging lambda-ish macro: wave w stages K rows 8w..8w+7, V dims 16w..16w+15 ---
#define STAGE_CHUNK(buf, kkv)                                                        \
  {                                                                                  \
    int kk_ = (kkv);                                                                 \
    _Pragma("unroll")                                                                \
    for (int j = 0; j < 2; j++) {                                                    \
      int rloc = wave * 8 + j * 4 + (lane >> 4);                                     \
      int oct = (lane & 15) ^ (rloc & 15);                                           \
      gld_lds16(Kg + (size_t)(kk_ + rloc) * 128 + oct * 8,                           \
                &Kbuf[buf][(wave * 8 + j * 4) * 128]);                               \
    }                                                                                \
    _Pragma("unroll")                                                                \
    for (int j = 0; j < 2; j++) {                                                    \
      int dloc = wave * 16 + j * 8 + (lane >> 3);                                    \
      int oct = (lane & 7) ^ (dloc & 7);                                             \
      gld_lds16(Vg + (size_t)dloc * T_SEQ + kk_ + oct * 8,                           \
                &Vbuf[buf][(wave * 16 + j * 8) * 64]);                               \
    }                                                                                \
  }

  STAGE_CHUNK(0, lo);
  int ib = 0;
  for (int kk = lo; kk < qbase + 64; kk += 64, ib ^= 1) {
    __syncthreads();  // staging of buf ib complete (vmcnt drained per-wave)
    if (kk + 64 < qbase + 64) STAGE_CHUNK(ib ^ 1, kk + 64);
    // wave-uniform skip: chunk outside this wave's rows' union window
    if (kk > q0 + 31 || kk + 63 < q0 - (WINDOW_SZ - 1)) continue;
    const unsigned short* kb = Kbuf[ib];
    const unsigned short* vb = Vbuf[ib];
    // S = Q K^T, K-frags shared by both q-tiles
    f32x4 sc[2][4] = {};
#pragma unroll
    for (int ks = 0; ks < 4; ks++) {
#pragma unroll
      for (int ci = 0; ci < 4; ci++) {
        s16x8 bk = *(const s16x8*)&kb[(ci * 16 + l16) * 128 + (((ks * 4 + quad) ^ l16) * 8)];
        sc[0][ci] = __builtin_amdgcn_mfma_f32_16x16x32_bf16(aq[0][ks], bk, sc[0][ci], 0, 0, 0);
        sc[1][ci] = __builtin_amdgcn_mfma_f32_16x16x32_bf16(aq[1][ks], bk, sc[1][ci], 0, 0, 0);
      }
    }
    // mask + exp2 + denominator + P to LDS (A-layout round trip)
#pragma unroll
    for (int qt = 0; qt < 2; qt++)
#pragma unroll
      for (int ci = 0; ci < 4; ci++) {
        int col = kk + ci * 16 + l16;
#pragma unroll
        for (int r = 0; r < 4; r++) {
          int irow = q0 + qt * 16 + quad * 4 + r;
          unsigned dd = (unsigned)(irow - col);
          float e = (dd < (unsigned)WINDOW_SZ) ? exp2f(sc[qt][ci][r]) : 0.f;
          lrow[qt][r] += e;
          Pbuf[wave][qt][(quad * 4 + r) * 72 + ci * 16 + l16] = f2bf(e);
        }
      }
    // O += P @ V, V-frags shared by both q-tiles
#pragma unroll
    for (int c = 0; c < 2; c++) {
      s16x8 pa0 = *(const s16x8*)&Pbuf[wave][0][l16 * 72 + c * 32 + quad * 8];
      s16x8 pa1 = *(const s16x8*)&Pbuf[wave][1][l16 * 72 + c * 32 + quad * 8];
#pragma unroll
      for (int n = 0; n < 8; n++) {
        s16x8 bv = *(const s16x8*)&vb[(n * 16 + l16) * 64 + (((c * 4 + quad) ^ (l16 & 7)) * 8)];
        acc[0][n] = __builtin_amdgcn_mfma_f32_16x16x32_bf16(pa0, bv, acc[0][n], 0, 0, 0);
        acc[1][n] = __builtin_amdgcn_mfma_f32_16x16x32_bf16(pa1, bv, acc[1][n], 0, 0, 0);
      }
    }
  }
#undef STAGE_CHUNK
  // denominator reduce across the 16 cols (l16 lanes of each quad) + output
#pragma unroll
  for (int qt = 0; qt < 2; qt++)
#pragma unroll
    for (int r = 0; r < 4; r++) {
#pragma unroll
      for (int off = 8; off; off >>= 1) lrow[qt][r] += __shfl_xor(lrow[qt][r], off);
      lrow[qt][r] = 1.f / lrow[qt][r];
    }
#pragma unroll
  for (int qt = 0; qt < 2; qt++)
#pragma unroll
    for (int n = 0; n < 8; n++)
#pragma unroll
      for (int r = 0; r < 4; r++) {
        int irow = q0 + qt * 16 + quad * 4 + r;
        Y[(size_t)irow * 4096 + h * 128 + n * 16 + l16] = f2bf(acc[qt][n][r] * lrow[qt][r]);
      }
}

extern "C" void kernel_launch(void* const* d_in, const int* in_sizes, int n_in,
                              void* d_out, int out_size, void* d_ws, size_t ws_size,
                              hipStream_t stream) {
  (void)in_sizes; (void)n_in; (void)out_size; (void)ws_size;
  const float* x     = (const float*)d_in[0];
  const float* cosb  = (const float*)d_in[1];
  const float* sinb  = (const float*)d_in[2];
  const float* Wqkv  = (const float*)d_in[3];
  const float* wq    = (const float*)d_in[4];
  const float* wk    = (const float*)d_in[5];
  const float* Wproj = (const float*)d_in[6];
  float* out = (float*)d_out;

  char* ws = (char*)d_ws;
  unsigned short* x_bf     = (unsigned short*)(ws);                 // 16 MB
  unsigned short* wqkv_bf  = (unsigned short*)(ws + 16777216);      // 48 MB
  unsigned short* wproj_bf = (unsigned short*)(ws + 67108864);      // 32 MB
  float*          qkv      = (float*)(ws + 100663296);              // 48 MB
  unsigned short* qr       = (unsigned short*)(ws + 150994944);     // 16 MB
  unsigned short* kr       = (unsigned short*)(ws + 167772160);     // 4 MB
  unsigned short* vt       = (unsigned short*)(ws + 171966464);     // 4 MB
  unsigned short* y        = (unsigned short*)(ws + 176160768);     // 16 MB

  cvt_bf16<<<(2097152 + 255) / 256, 256, 0, stream>>>(x, x_bf, 2097152);
  cvt_bf16<<<(6291456 + 255) / 256, 256, 0, stream>>>(Wqkv, wqkv_bf, 6291456);
  cvt_bf16<<<(4194304 + 255) / 256, 256, 0, stream>>>(Wproj, wproj_bf, 4194304);
  gemm_bt<<<dim3(48, 16), 256, 0, stream>>>(x_bf, wqkv_bf, qkv, 2048, 6144, 4096);
  normrope<<<2048, 256, 0, stream>>>(qkv, cosb, sinb, wq, wk, qr, kr, vt);
  attn<<<dim3(32, 8), 512, 0, stream>>>(qr, kr, vt, y);
  gemm_bt<<<dim3(32, 16), 256, 0, stream>>>(y, wproj_bf, out, 2048, 4096, 4096);
}

// Round 4
// 519.799 us; speedup vs baseline: 1.5422x; 1.0844x over previous
//
#include <hip/hip_runtime.h>
#include <stdint.h>
#include <stddef.h>
#include <type_traits>

#define T_SEQ 2048
#define WINDOW_SZ 1024

typedef __attribute__((ext_vector_type(4))) float f32x4;
typedef __attribute__((ext_vector_type(8))) short s16x8;
typedef __attribute__((ext_vector_type(4))) short s16x4;

__device__ inline unsigned short f2bf(float f) {
  union { float f; unsigned u; } v; v.f = f;
  unsigned u = v.u;
  return (unsigned short)((u + 0x7fffu + ((u >> 16) & 1u)) >> 16);
}
__device__ inline float bf2f(unsigned short u) {
  union { unsigned u; float f; } v; v.u = ((unsigned)u) << 16; return v.f;
}

__device__ inline void gld_lds16(const unsigned short* g, unsigned short* l) {
  __builtin_amdgcn_global_load_lds((const __attribute__((address_space(1))) void*)g,
                                   (__attribute__((address_space(3))) void*)l, 16, 0, 0);
}

__device__ inline void store_out(float* p, float v) { *p = v; }
__device__ inline void store_out(unsigned short* p, float v) { *p = f2bf(v); }

// ---------------- fp32 -> bf16 convert (vectorized) ----------------
__global__ __launch_bounds__(256) void cvt_bf16(const float* __restrict__ s,
                                                unsigned short* __restrict__ d, int n4) {
  int i = blockIdx.x * 256 + threadIdx.x;
  if (i >= n4) return;
  float4 v = ((const float4*)s)[i];
  ushort4 o;
  o.x = f2bf(v.x); o.y = f2bf(v.y); o.z = f2bf(v.z); o.w = f2bf(v.w);
  ((ushort4*)d)[i] = o;
}

// ---------------- bf16 GEMM: C[M,N] = A[M,K] @ Bt[N,K]^T ----------------
// BK=64 (32 MFMA per barrier pair), XOR-swizzled LDS (conflict-free b128 frag
// reads; swizzle realized by per-lane source remap at staging), templated
// output type (bf16 for QKV, fp32 for final proj).
template <typename OutT>
__global__ __launch_bounds__(256) void gemm_bt(const unsigned short* __restrict__ A,
                                               const unsigned short* __restrict__ Bt,
                                               OutT* __restrict__ C, int M, int N, int K) {
  __shared__ unsigned short As[128 * 64];  // 16 KB, row r chunk c at r*64+(c^(r&7))*8
  __shared__ unsigned short Bs[128 * 64];
  const int tid  = threadIdx.x;
  const int wave = tid >> 6, lane = tid & 63;
  const int quad = lane >> 4, l16 = lane & 15;
  const int m0 = blockIdx.y << 7, n0 = blockIdx.x << 7;
  const int wr = (wave >> 1) << 6;
  const int wc = (wave & 1) << 6;
  const int srow = wave * 8 + (lane >> 3);       // staging row within 32-group
  const int gchunk0 = lane & 7;                  // phys chunk = lane&7

  f32x4 acc[4][4] = {};

  for (int k0 = 0; k0 < K; k0 += 64) {
#pragma unroll
    for (int j = 0; j < 4; j++) {
      int r = j * 32 + srow;
      int gc = gchunk0 ^ (r & 7);
      gld_lds16(A  + (size_t)(m0 + r) * K + k0 + gc * 8, &As[(j * 32 + wave * 8) * 64]);
      gld_lds16(Bt + (size_t)(n0 + r) * K + k0 + gc * 8, &Bs[(j * 32 + wave * 8) * 64]);
    }
    __syncthreads();
#pragma unroll
    for (int s = 0; s < 2; s++) {
      s16x8 af[4], bfr[4];
#pragma unroll
      for (int i = 0; i < 4; i++) {
        int ra = wr + i * 16 + l16;
        af[i]  = *(const s16x8*)&As[ra * 64 + (((s * 4 + quad) ^ (ra & 7)) * 8)];
        int rb = wc + i * 16 + l16;
        bfr[i] = *(const s16x8*)&Bs[rb * 64 + (((s * 4 + quad) ^ (rb & 7)) * 8)];
      }
#pragma unroll
      for (int mi = 0; mi < 4; mi++)
#pragma unroll
        for (int ni = 0; ni < 4; ni++)
          acc[mi][ni] = __builtin_amdgcn_mfma_f32_16x16x32_bf16(af[mi], bfr[ni], acc[mi][ni], 0, 0, 0);
    }
    __syncthreads();
  }
#pragma unroll
  for (int mi = 0; mi < 4; mi++)
#pragma unroll
    for (int ni = 0; ni < 4; ni++) {
      int row = m0 + wr + mi * 16 + quad * 4;
      int col = n0 + wc + ni * 16 + l16;
#pragma unroll
      for (int r = 0; r < 4; r++)
        store_out(&C[(size_t)(row + r) * N + col], acc[mi][ni][r]);
    }
}

// ---------------- fused RMSNorm + RoPE + layout (one block per token) ----------------
// qkv bf16 [T][6144] -> qr bf16 [32][T][128] (PRE-SCALED by log2(e)/sqrt(128)),
// kr bf16 [8][T][128], vt bf16 [8][128][T]
__global__ __launch_bounds__(256) void normrope(const unsigned short* __restrict__ qkv,
                                                const float* __restrict__ cosb,
                                                const float* __restrict__ sinb,
                                                const float* __restrict__ wq,
                                                const float* __restrict__ wk,
                                                unsigned short* __restrict__ qr,
                                                unsigned short* __restrict__ kr,
                                                unsigned short* __restrict__ vt) {
  const int t = blockIdx.x, tid = threadIdx.x;
  const unsigned short* row = qkv + (size_t)t * 6144;
  float sq = 0.f, sk = 0.f;
  {
    s16x8 a = *(const s16x8*)&row[tid * 16];
    s16x8 b = *(const s16x8*)&row[tid * 16 + 8];
#pragma unroll
    for (int j = 0; j < 8; j++) {
      float fa = bf2f((unsigned short)a[j]), fb = bf2f((unsigned short)b[j]);
      sq += fa * fa + fb * fb;
    }
  }
  {
    s16x4 a = *(const s16x4*)&row[4096 + tid * 4];
#pragma unroll
    for (int j = 0; j < 4; j++) {
      float fa = bf2f((unsigned short)a[j]);
      sk += fa * fa;
    }
  }
#pragma unroll
  for (int off = 32; off; off >>= 1) { sq += __shfl_xor(sq, off); sk += __shfl_xor(sk, off); }
  __shared__ float red[8];
  if ((tid & 63) == 0) { red[tid >> 6] = sq; red[4 + (tid >> 6)] = sk; }
  __syncthreads();
  sq = red[0] + red[1] + red[2] + red[3];
  sk = red[4] + red[5] + red[6] + red[7];
  // fold 1/sqrt(HEAD) and log2(e) into q scale: attn uses exp2 (exact identity)
  const float rq = rsqrtf(sq * (1.f / 4096.f) + 1e-5f) * (0.08838834764831845f * 1.4426950408889634f);
  const float rk = rsqrtf(sk * (1.f / 1024.f) + 1e-5f);
  for (int i = tid; i < 4096; i += 256) {
    int h = i >> 7, d = i & 127;
    int pd = (d < 64) ? d + 64 : d - 64;
    float val = bf2f(row[i]) * rq * wq[i];
    float pv  = bf2f(row[(h << 7) + pd]) * rq * wq[(h << 7) + pd];
    float rot = (d < 64) ? -pv : pv;
    float o = val * cosb[t * 128 + d] + rot * sinb[t * 128 + d];
    qr[(size_t)h * T_SEQ * 128 + t * 128 + d] = f2bf(o);
  }
  for (int i = tid; i < 1024; i += 256) {
    int g = i >> 7, d = i & 127;
    int pd = (d < 64) ? d + 64 : d - 64;
    float val = bf2f(row[4096 + i]) * rk * wk[i];
    float pv  = bf2f(row[4096 + (g << 7) + pd]) * rk * wk[(g << 7) + pd];
    float rot = (d < 64) ? -pv : pv;
    float o = val * cosb[t * 128 + d] + rot * sinb[t * 128 + d];
    kr[(size_t)g * T_SEQ * 128 + t * 128 + d] = f2bf(o);
  }
  for (int i = tid; i < 1024; i += 256) {
    int g = i >> 7, d = i & 127;
    vt[(size_t)g * 128 * T_SEQ + (size_t)d * T_SEQ + t] = row[5120 + i];  // already bf16
  }
}

// ---------------- flash attention, sliding window, block-shared LDS K/V ----------------
__global__ __launch_bounds__(512, 2) void attn(const unsigned short* __restrict__ Q,
                                               const unsigned short* __restrict__ Kb,
                                               const unsigned short* __restrict__ Vt,
                                               unsigned short* __restrict__ Y) {
  __shared__ unsigned short Kbuf[2][64 * 128];
  __shared__ unsigned short Vbuf[2][128 * 64];
  __shared__ unsigned short Pbuf[8][2][16 * 72];
  const int qb = blockIdx.x, g = blockIdx.y;
  const int tid = threadIdx.x, wave = tid >> 6, lane = tid & 63;
  const int quad = lane >> 4, l16 = lane & 15;
  const int h = g * 4 + (wave >> 1);
  const int qbase = qb * 64;
  const int q0 = qbase + (wave & 1) * 32;
  const unsigned short* Qh = Q + (size_t)h * T_SEQ * 128;
  const unsigned short* Kg = Kb + (size_t)g * T_SEQ * 128;
  const unsigned short* Vg = Vt + (size_t)g * 128 * T_SEQ;

  s16x8 aq[2][4];
#pragma unroll
  for (int qt = 0; qt < 2; qt++)
#pragma unroll
    for (int ks = 0; ks < 4; ks++)
      aq[qt][ks] = *(const s16x8*)&Qh[(size_t)(q0 + qt * 16 + l16) * 128 + ks * 32 + quad * 8];

  f32x4 acc[2][8] = {};
  float lrow[2][4] = {};

  int lo = qbase - (WINDOW_SZ - 1);
  if (lo < 0) lo = 0;
  lo &= ~63;

#define STAGE_CHUNK(buf, kkv)                                                        \
  {                                                                                  \
    int kk_ = (kkv);                                                                 \
    _Pragma("unroll")                                                                \
    for (int j = 0; j < 2; j++) {                                                    \
      int rloc = wave * 8 + j * 4 + (lane >> 4);                                     \
      int oct = (lane & 15) ^ (rloc & 15);                                           \
      gld_lds16(Kg + (size_t)(kk_ + rloc) * 128 + oct * 8,                           \
                &Kbuf[buf][(wave * 8 + j * 4) * 128]);                               \
    }                                                                                \
    _Pragma("unroll")                                                                \
    for (int j = 0; j < 2; j++) {                                                    \
      int dloc = wave * 16 + j * 8 + (lane >> 3);                                    \
      int oct = (lane & 7) ^ (dloc & 7);                                             \
      gld_lds16(Vg + (size_t)dloc * T_SEQ + kk_ + oct * 8,                           \
                &Vbuf[buf][(wave * 16 + j * 8) * 64]);                               \
    }                                                                                \
  }

  STAGE_CHUNK(0, lo);
  int ib = 0;
  for (int kk = lo; kk < qbase + 64; kk += 64, ib ^= 1) {
    __syncthreads();
    if (kk + 64 < qbase + 64) STAGE_CHUNK(ib ^ 1, kk + 64);
    if (kk > q0 + 31 || kk + 63 < q0 - (WINDOW_SZ - 1)) continue;
    const unsigned short* kb = Kbuf[ib];
    const unsigned short* vb = Vbuf[ib];
    f32x4 sc[2][4] = {};
#pragma unroll
    for (int ks = 0; ks < 4; ks++) {
#pragma unroll
      for (int ci = 0; ci < 4; ci++) {
        s16x8 bk = *(const s16x8*)&kb[(ci * 16 + l16) * 128 + (((ks * 4 + quad) ^ l16) * 8)];
        sc[0][ci] = __builtin_amdgcn_mfma_f32_16x16x32_bf16(aq[0][ks], bk, sc[0][ci], 0, 0, 0);
        sc[1][ci] = __builtin_amdgcn_mfma_f32_16x16x32_bf16(aq[1][ks], bk, sc[1][ci], 0, 0, 0);
      }
    }
#pragma unroll
    for (int qt = 0; qt < 2; qt++)
#pragma unroll
      for (int ci = 0; ci < 4; ci++) {
        int col = kk + ci * 16 + l16;
#pragma unroll
        for (int r = 0; r < 4; r++) {
          int irow = q0 + qt * 16 + quad * 4 + r;
          unsigned dd = (unsigned)(irow - col);
          float e = (dd < (unsigned)WINDOW_SZ) ? exp2f(sc[qt][ci][r]) : 0.f;
          lrow[qt][r] += e;
          Pbuf[wave][qt][(quad * 4 + r) * 72 + ci * 16 + l16] = f2bf(e);
        }
      }
#pragma unroll
    for (int c = 0; c < 2; c++) {
      s16x8 pa0 = *(const s16x8*)&Pbuf[wave][0][l16 * 72 + c * 32 + quad * 8];
      s16x8 pa1 = *(const s16x8*)&Pbuf[wave][1][l16 * 72 + c * 32 + quad * 8];
#pragma unroll
      for (int n = 0; n < 8; n++) {
        s16x8 bv = *(const s16x8*)&vb[(n * 16 + l16) * 64 + (((c * 4 + quad) ^ (l16 & 7)) * 8)];
        acc[0][n] = __builtin_amdgcn_mfma_f32_16x16x32_bf16(pa0, bv, acc[0][n], 0, 0, 0);
        acc[1][n] = __builtin_amdgcn_mfma_f32_16x16x32_bf16(pa1, bv, acc[1][n], 0, 0, 0);
      }
    }
  }
#undef STAGE_CHUNK
#pragma unroll
  for (int qt = 0; qt < 2; qt++)
#pragma unroll
    for (int r = 0; r < 4; r++) {
#pragma unroll
      for (int off = 8; off; off >>= 1) lrow[qt][r] += __shfl_xor(lrow[qt][r], off);
      lrow[qt][r] = 1.f / lrow[qt][r];
    }
#pragma unroll
  for (int qt = 0; qt < 2; qt++)
#pragma unroll
    for (int n = 0; n < 8; n++)
#pragma unroll
      for (int r = 0; r < 4; r++) {
        int irow = q0 + qt * 16 + quad * 4 + r;
        Y[(size_t)irow * 4096 + h * 128 + n * 16 + l16] = f2bf(acc[qt][n][r] * lrow[qt][r]);
      }
}

extern "C" void kernel_launch(void* const* d_in, const int* in_sizes, int n_in,
                              void* d_out, int out_size, void* d_ws, size_t ws_size,
                              hipStream_t stream) {
  (void)in_sizes; (void)n_in; (void)out_size; (void)ws_size;
  const float* x     = (const float*)d_in[0];
  const float* cosb  = (const float*)d_in[1];
  const float* sinb  = (const float*)d_in[2];
  const float* Wqkv  = (const float*)d_in[3];
  const float* wq    = (const float*)d_in[4];
  const float* wk    = (const float*)d_in[5];
  const float* Wproj = (const float*)d_in[6];
  float* out = (float*)d_out;

  char* ws = (char*)d_ws;
  unsigned short* x_bf     = (unsigned short*)(ws);                 // 16 MB
  unsigned short* wqkv_bf  = (unsigned short*)(ws + 16777216);      // 48 MB
  unsigned short* wproj_bf = (unsigned short*)(ws + 67108864);      // 32 MB
  unsigned short* qkv      = (unsigned short*)(ws + 100663296);     // 24 MB (bf16 now)
  unsigned short* qr       = (unsigned short*)(ws + 150994944);     // 16 MB
  unsigned short* kr       = (unsigned short*)(ws + 167772160);     // 4 MB
  unsigned short* vt       = (unsigned short*)(ws + 171966464);     // 4 MB
  unsigned short* y        = (unsigned short*)(ws + 176160768);     // 16 MB

  cvt_bf16<<<(2097152 + 255) / 256, 256, 0, stream>>>(x, x_bf, 2097152);
  cvt_bf16<<<(6291456 + 255) / 256, 256, 0, stream>>>(Wqkv, wqkv_bf, 6291456);
  cvt_bf16<<<(4194304 + 255) / 256, 256, 0, stream>>>(Wproj, wproj_bf, 4194304);
  gemm_bt<unsigned short><<<dim3(48, 16), 256, 0, stream>>>(x_bf, wqkv_bf, qkv, 2048, 6144, 4096);
  normrope<<<2048, 256, 0, stream>>>(qkv, cosb, sinb, wq, wk, qr, kr, vt);
  attn<<<dim3(32, 8), 512, 0, stream>>>(qr, kr, vt, y);
  gemm_bt<float><<<dim3(32, 16), 256, 0, stream>>>(y, wproj_bf, out, 2048, 4096, 4096);
}

// Round 5
// 497.208 us; speedup vs baseline: 1.6123x; 1.0454x over previous
//
#include <hip/hip_runtime.h>
#include <stdint.h>
#include <stddef.h>

#define T_SEQ 2048
#define WINDOW_SZ 1024

typedef __attribute__((ext_vector_type(4))) float f32x4;
typedef __attribute__((ext_vector_type(16))) float f32x16;
typedef __attribute__((ext_vector_type(8))) short s16x8;
typedef __attribute__((ext_vector_type(4))) short s16x4;

__device__ inline unsigned short f2bf(float f) {
  union { float f; unsigned u; } v; v.f = f;
  unsigned u = v.u;
  return (unsigned short)((u + 0x7fffu + ((u >> 16) & 1u)) >> 16);
}
__device__ inline float bf2f(unsigned short u) {
  union { unsigned u; float f; } v; v.u = ((unsigned)u) << 16; return v.f;
}

__device__ inline void gld_lds16(const unsigned short* g, unsigned short* l) {
  __builtin_amdgcn_global_load_lds((const __attribute__((address_space(1))) void*)g,
                                   (__attribute__((address_space(3))) void*)l, 16, 0, 0);
}

__device__ inline void store_out(float* p, float v) { *p = v; }
__device__ inline void store_out(unsigned short* p, float v) { *p = f2bf(v); }

// ---------------- fused fp32 -> bf16 convert for x, W_qkv, W_proj ----------------
// one launch; i indexes float4s across the concatenation
__global__ __launch_bounds__(256) void cvt_all(const float* __restrict__ x,
                                               const float* __restrict__ wqkv,
                                               const float* __restrict__ wproj,
                                               unsigned short* __restrict__ x_bf,
                                               unsigned short* __restrict__ wqkv_bf,
                                               unsigned short* __restrict__ wproj_bf) {
  int i = blockIdx.x * 256 + threadIdx.x;  // 0 .. 12582912-1 float4s
  const float* s; unsigned short* d; int j;
  if (i < 2097152)       { s = x;     d = x_bf;     j = i; }
  else if (i < 8388608)  { s = wqkv;  d = wqkv_bf;  j = i - 2097152; }
  else                   { s = wproj; d = wproj_bf; j = i - 8388608; }
  float4 v = ((const float4*)s)[j];
  ushort4 o;
  o.x = f2bf(v.x); o.y = f2bf(v.y); o.z = f2bf(v.z); o.w = f2bf(v.w);
  ((ushort4*)d)[j] = o;
}

// ---------------- bf16 GEMM: C[M,N] = A[M,K] @ Bt[N,K]^T ----------------
// 128x128 tile, BK=64, XOR-swizzled LDS (conflict-free, verified R4), and
// 32x32x16 MFMA (4060 FLOP/cyc vs 3378 for 16x16x32 — m119). Wave = 64x64
// as 2x2 frags of 32x32. Templated output (bf16 for QKV, fp32 for proj).
template <typename OutT>
__global__ __launch_bounds__(256) void gemm_bt(const unsigned short* __restrict__ A,
                                               const unsigned short* __restrict__ Bt,
                                               OutT* __restrict__ C, int M, int N, int K) {
  __shared__ unsigned short As[128 * 64];  // row r chunk c at r*64+(c^(r&7))*8
  __shared__ unsigned short Bs[128 * 64];
  const int tid  = threadIdx.x;
  const int wave = tid >> 6, lane = tid & 63;
  const int l32 = lane & 31, khalf = lane >> 5;
  const int m0 = blockIdx.y << 7, n0 = blockIdx.x << 7;
  const int wr = (wave >> 1) << 6;
  const int wc = (wave & 1) << 6;
  const int srow = wave * 8 + (lane >> 3);       // staging row within 32-group
  const int gchunk0 = lane & 7;                  // phys chunk = lane&7

  f32x16 acc[2][2] = {};

  for (int k0 = 0; k0 < K; k0 += 64) {
#pragma unroll
    for (int j = 0; j < 4; j++) {
      int r = j * 32 + srow;
      int gc = gchunk0 ^ (r & 7);
      gld_lds16(A  + (size_t)(m0 + r) * K + k0 + gc * 8, &As[(j * 32 + wave * 8) * 64]);
      gld_lds16(Bt + (size_t)(n0 + r) * K + k0 + gc * 8, &Bs[(j * 32 + wave * 8) * 64]);
    }
    __syncthreads();
#pragma unroll
    for (int s = 0; s < 4; s++) {       // K-steps of 16
      s16x8 af[2], bfr[2];
      int chunk = s * 2 + khalf;        // logical 16B chunk index (k = chunk*8)
#pragma unroll
      for (int i = 0; i < 2; i++) {
        int ra = wr + i * 32 + l32;
        af[i]  = *(const s16x8*)&As[ra * 64 + ((chunk ^ (ra & 7)) * 8)];
        int rb = wc + i * 32 + l32;
        bfr[i] = *(const s16x8*)&Bs[rb * 64 + ((chunk ^ (rb & 7)) * 8)];
      }
#pragma unroll
      for (int mi = 0; mi < 2; mi++)
#pragma unroll
        for (int ni = 0; ni < 2; ni++)
          acc[mi][ni] = __builtin_amdgcn_mfma_f32_32x32x16_bf16(af[mi], bfr[ni], acc[mi][ni], 0, 0, 0);
    }
    __syncthreads();
  }
  // C/D: col = lane&31, row = (reg&3) + 8*(reg>>2) + 4*(lane>>5)   [m74/m101]
#pragma unroll
  for (int mi = 0; mi < 2; mi++)
#pragma unroll
    for (int ni = 0; ni < 2; ni++) {
      int col = n0 + wc + ni * 32 + l32;
      int rbase = m0 + wr + mi * 32 + 4 * khalf;
#pragma unroll
      for (int reg = 0; reg < 16; reg++) {
        int row = rbase + (reg & 3) + 8 * (reg >> 2);
        store_out(&C[(size_t)row * N + col], acc[mi][ni][reg]);
      }
    }
}

// ---------------- fused RMSNorm + RoPE + layout (one block per token) ----------------
// qkv bf16 [T][6144] -> qr bf16 [32][T][128] (PRE-SCALED by log2(e)/sqrt(128)),
// kr bf16 [8][T][128], vt bf16 [8][128][T]
__global__ __launch_bounds__(256) void normrope(const unsigned short* __restrict__ qkv,
                                                const float* __restrict__ cosb,
                                                const float* __restrict__ sinb,
                                                const float* __restrict__ wq,
                                                const float* __restrict__ wk,
                                                unsigned short* __restrict__ qr,
                                                unsigned short* __restrict__ kr,
                                                unsigned short* __restrict__ vt) {
  const int t = blockIdx.x, tid = threadIdx.x;
  const unsigned short* row = qkv + (size_t)t * 6144;
  float sq = 0.f, sk = 0.f;
  {
    s16x8 a = *(const s16x8*)&row[tid * 16];
    s16x8 b = *(const s16x8*)&row[tid * 16 + 8];
#pragma unroll
    for (int j = 0; j < 8; j++) {
      float fa = bf2f((unsigned short)a[j]), fb = bf2f((unsigned short)b[j]);
      sq += fa * fa + fb * fb;
    }
  }
  {
    s16x4 a = *(const s16x4*)&row[4096 + tid * 4];
#pragma unroll
    for (int j = 0; j < 4; j++) {
      float fa = bf2f((unsigned short)a[j]);
      sk += fa * fa;
    }
  }
#pragma unroll
  for (int off = 32; off; off >>= 1) { sq += __shfl_xor(sq, off); sk += __shfl_xor(sk, off); }
  __shared__ float red[8];
  if ((tid & 63) == 0) { red[tid >> 6] = sq; red[4 + (tid >> 6)] = sk; }
  __syncthreads();
  sq = red[0] + red[1] + red[2] + red[3];
  sk = red[4] + red[5] + red[6] + red[7];
  const float rq = rsqrtf(sq * (1.f / 4096.f) + 1e-5f) * (0.08838834764831845f * 1.4426950408889634f);
  const float rk = rsqrtf(sk * (1.f / 1024.f) + 1e-5f);
  for (int i = tid; i < 4096; i += 256) {
    int h = i >> 7, d = i & 127;
    int pd = (d < 64) ? d + 64 : d - 64;
    float val = bf2f(row[i]) * rq * wq[i];
    float pv  = bf2f(row[(h << 7) + pd]) * rq * wq[(h << 7) + pd];
    float rot = (d < 64) ? -pv : pv;
    float o = val * cosb[t * 128 + d] + rot * sinb[t * 128 + d];
    qr[(size_t)h * T_SEQ * 128 + t * 128 + d] = f2bf(o);
  }
  for (int i = tid; i < 1024; i += 256) {
    int g = i >> 7, d = i & 127;
    int pd = (d < 64) ? d + 64 : d - 64;
    float val = bf2f(row[4096 + i]) * rk * wk[i];
    float pv  = bf2f(row[4096 + (g << 7) + pd]) * rk * wk[(g << 7) + pd];
    float rot = (d < 64) ? -pv : pv;
    float o = val * cosb[t * 128 + d] + rot * sinb[t * 128 + d];
    kr[(size_t)g * T_SEQ * 128 + t * 128 + d] = f2bf(o);
  }
  for (int i = tid; i < 1024; i += 256) {
    int g = i >> 7, d = i & 127;
    vt[(size_t)g * 128 * T_SEQ + (size_t)d * T_SEQ + t] = row[5120 + i];
  }
}

// ---------------- flash attention, sliding window, block-shared LDS K/V ----------------
__global__ __launch_bounds__(512, 2) void attn(const unsigned short* __restrict__ Q,
                                               const unsigned short* __restrict__ Kb,
                                               const unsigned short* __restrict__ Vt,
                                               unsigned short* __restrict__ Y) {
  __shared__ unsigned short Kbuf[2][64 * 128];
  __shared__ unsigned short Vbuf[2][128 * 64];
  __shared__ unsigned short Pbuf[8][2][16 * 72];
  const int qb = blockIdx.x, g = blockIdx.y;
  const int tid = threadIdx.x, wave = tid >> 6, lane = tid & 63;
  const int quad = lane >> 4, l16 = lane & 15;
  const int h = g * 4 + (wave >> 1);
  const int qbase = qb * 64;
  const int q0 = qbase + (wave & 1) * 32;
  const unsigned short* Qh = Q + (size_t)h * T_SEQ * 128;
  const unsigned short* Kg = Kb + (size_t)g * T_SEQ * 128;
  const unsigned short* Vg = Vt + (size_t)g * 128 * T_SEQ;

  s16x8 aq[2][4];
#pragma unroll
  for (int qt = 0; qt < 2; qt++)
#pragma unroll
    for (int ks = 0; ks < 4; ks++)
      aq[qt][ks] = *(const s16x8*)&Qh[(size_t)(q0 + qt * 16 + l16) * 128 + ks * 32 + quad * 8];

  f32x4 acc[2][8] = {};
  float lrow[2][4] = {};

  int lo = qbase - (WINDOW_SZ - 1);
  if (lo < 0) lo = 0;
  lo &= ~63;

#define STAGE_CHUNK(buf, kkv)                                                        \
  {                                                                                  \
    int kk_ = (kkv);                                                                 \
    _Pragma("unroll")                                                                \
    for (int j = 0; j < 2; j++) {                                                    \
      int rloc = wave * 8 + j * 4 + (lane >> 4);                                     \
      int oct = (lane & 15) ^ (rloc & 15);                                           \
      gld_lds16(Kg + (size_t)(kk_ + rloc) * 128 + oct * 8,                           \
                &Kbuf[buf][(wave * 8 + j * 4) * 128]);                               \
    }                                                                                \
    _Pragma("unroll")                                                                \
    for (int j = 0; j < 2; j++) {                                                    \
      int dloc = wave * 16 + j * 8 + (lane >> 3);                                    \
      int oct = (lane & 7) ^ (dloc & 7);                                             \
      gld_lds16(Vg + (size_t)dloc * T_SEQ + kk_ + oct * 8,                           \
                &Vbuf[buf][(wave * 16 + j * 8) * 64]);                               \
    }                                                                                \
  }

  STAGE_CHUNK(0, lo);
  int ib = 0;
  for (int kk = lo; kk < qbase + 64; kk += 64, ib ^= 1) {
    __syncthreads();
    if (kk + 64 < qbase + 64) STAGE_CHUNK(ib ^ 1, kk + 64);
    if (kk > q0 + 31 || kk + 63 < q0 - (WINDOW_SZ - 1)) continue;
    const unsigned short* kb = Kbuf[ib];
    const unsigned short* vb = Vbuf[ib];
    f32x4 sc[2][4] = {};
#pragma unroll
    for (int ks = 0; ks < 4; ks++) {
#pragma unroll
      for (int ci = 0; ci < 4; ci++) {
        s16x8 bk = *(const s16x8*)&kb[(ci * 16 + l16) * 128 + (((ks * 4 + quad) ^ l16) * 8)];
        sc[0][ci] = __builtin_amdgcn_mfma_f32_16x16x32_bf16(aq[0][ks], bk, sc[0][ci], 0, 0, 0);
        sc[1][ci] = __builtin_amdgcn_mfma_f32_16x16x32_bf16(aq[1][ks], bk, sc[1][ci], 0, 0, 0);
      }
    }
#pragma unroll
    for (int qt = 0; qt < 2; qt++)
#pragma unroll
      for (int ci = 0; ci < 4; ci++) {
        int col = kk + ci * 16 + l16;
#pragma unroll
        for (int r = 0; r < 4; r++) {
          int irow = q0 + qt * 16 + quad * 4 + r;
          unsigned dd = (unsigned)(irow - col);
          float e = (dd < (unsigned)WINDOW_SZ) ? exp2f(sc[qt][ci][r]) : 0.f;
          lrow[qt][r] += e;
          Pbuf[wave][qt][(quad * 4 + r) * 72 + ci * 16 + l16] = f2bf(e);
        }
      }
#pragma unroll
    for (int c = 0; c < 2; c++) {
      s16x8 pa0 = *(const s16x8*)&Pbuf[wave][0][l16 * 72 + c * 32 + quad * 8];
      s16x8 pa1 = *(const s16x8*)&Pbuf[wave][1][l16 * 72 + c * 32 + quad * 8];
#pragma unroll
      for (int n = 0; n < 8; n++) {
        s16x8 bv = *(const s16x8*)&vb[(n * 16 + l16) * 64 + (((c * 4 + quad) ^ (l16 & 7)) * 8)];
        acc[0][n] = __builtin_amdgcn_mfma_f32_16x16x32_bf16(pa0, bv, acc[0][n], 0, 0, 0);
        acc[1][n] = __builtin_amdgcn_mfma_f32_16x16x32_bf16(pa1, bv, acc[1][n], 0, 0, 0);
      }
    }
  }
#undef STAGE_CHUNK
#pragma unroll
  for (int qt = 0; qt < 2; qt++)
#pragma unroll
    for (int r = 0; r < 4; r++) {
#pragma unroll
      for (int off = 8; off; off >>= 1) lrow[qt][r] += __shfl_xor(lrow[qt][r], off);
      lrow[qt][r] = 1.f / lrow[qt][r];
    }
#pragma unroll
  for (int qt = 0; qt < 2; qt++)
#pragma unroll
    for (int n = 0; n < 8; n++)
#pragma unroll
      for (int r = 0; r < 4; r++) {
        int irow = q0 + qt * 16 + quad * 4 + r;
        Y[(size_t)irow * 4096 + h * 128 + n * 16 + l16] = f2bf(acc[qt][n][r] * lrow[qt][r]);
      }
}

extern "C" void kernel_launch(void* const* d_in, const int* in_sizes, int n_in,
                              void* d_out, int out_size, void* d_ws, size_t ws_size,
                              hipStream_t stream) {
  (void)in_sizes; (void)n_in; (void)out_size; (void)ws_size;
  const float* x     = (const float*)d_in[0];
  const float* cosb  = (const float*)d_in[1];
  const float* sinb  = (const float*)d_in[2];
  const float* Wqkv  = (const float*)d_in[3];
  const float* wq    = (const float*)d_in[4];
  const float* wk    = (const float*)d_in[5];
  const float* Wproj = (const float*)d_in[6];
  float* out = (float*)d_out;

  char* ws = (char*)d_ws;
  unsigned short* x_bf     = (unsigned short*)(ws);                 // 16 MB
  unsigned short* wqkv_bf  = (unsigned short*)(ws + 16777216);      // 48 MB
  unsigned short* wproj_bf = (unsigned short*)(ws + 67108864);      // 32 MB
  unsigned short* qkv      = (unsigned short*)(ws + 100663296);     // 24 MB (bf16)
  unsigned short* qr       = (unsigned short*)(ws + 150994944);     // 16 MB
  unsigned short* kr       = (unsigned short*)(ws + 167772160);     // 4 MB
  unsigned short* vt       = (unsigned short*)(ws + 171966464);     // 4 MB
  unsigned short* y        = (unsigned short*)(ws + 176160768);     // 16 MB

  cvt_all<<<49152, 256, 0, stream>>>(x, Wqkv, Wproj, x_bf, wqkv_bf, wproj_bf);
  gemm_bt<unsigned short><<<dim3(48, 16), 256, 0, stream>>>(x_bf, wqkv_bf, qkv, 2048, 6144, 4096);
  normrope<<<2048, 256, 0, stream>>>(qkv, cosb, sinb, wq, wk, qr, kr, vt);
  attn<<<dim3(32, 8), 512, 0, stream>>>(qr, kr, vt, y);
  gemm_bt<float><<<dim3(32, 16), 256, 0, stream>>>(y, wproj_bf, out, 2048, 4096, 4096);
}